// Round 1
// baseline (10018.805 us; speedup 1.0000x reference)
//
#include <hip/hip_runtime.h>
#include <hip/hip_bf16.h>
#include <float.h>

#define NN 3072
#define MM 3072
#define DD 64
#define KK 8
#define NPROB 24

constexpr float C_EPS   = 0.0025f;   // blur^2
constexpr float C_SCAL2 = 0.64f;     // scaling^2
constexpr int   C_NITER = 30;
constexpr float LOG2E = 1.4426950408889634f;
constexpr float LN2F  = 0.6931471805599453f;

__device__ __forceinline__ float ex2(float x){ return __builtin_amdgcn_exp2f(x); }
__device__ __forceinline__ float lg2(float x){ return __builtin_amdgcn_logf(x); }

// workspace layout in 4-byte units
#define U_FILL 0        // 8 floats  (zeroed)
#define U_MAXC 8        // 4 uints   (zeroed)
#define U_CNTX 12       // 8 int     (zeroed)
#define U_CNTY 20       // 8 int     (zeroed)
#define U_POSX 28       // 8 int     (zeroed)
#define U_POSY 36       // 8 int     (zeroed)
#define U_OFFX 44       // 9 int
#define U_OFFY 53       // 9 int
#define U_PNX  64       // 24 int
#define U_PNY  88
#define U_PRB  112
#define U_PCB  136
#define U_PRS  160
#define U_PCS  184
#define U_PCOFF 208     // 25 int
#define U_TOFF  233     // 25 int
#define U_XSQ  320      // 3072 float
#define U_YSQ  3392     // 3072 float
#define U_PRED 6464     // 3072 int
#define U_ROWS 9536     // 3072 int
#define U_COLS 12608    // 3072 int
#define U_SUBC 16384    // compact submatrices (floats)

// ---------------- kernel 1: per-x-point: norms, argmin, softmax filling ----------------
__global__ __launch_bounds__(256) void k_prep_x(const float* __restrict__ x,
                                                const float* __restrict__ cc,
                                                float* wf, int* wi) {
    __shared__ __align__(16) float c_s[KK][DD];
    __shared__ float csq_s[KK];
    __shared__ float fpart[KK];
    int tid = threadIdx.x;
    for (int e = tid; e < KK*DD; e += 256) c_s[e>>6][e&63] = cc[e];
    if (tid < KK) fpart[tid] = 0.f;
    __syncthreads();
    if (tid < KK) { float s=0.f; for (int d=0; d<DD; ++d){ float v=c_s[tid][d]; s+=v*v; } csq_s[tid]=s; }
    __syncthreads();
    int i = blockIdx.x*256 + tid;
    if (i < NN) {
        const float4* xr = (const float4*)(x + (size_t)i*DD);
        float4 xv[16];
        float xs = 0.f;
        #pragma unroll
        for (int q=0;q<16;++q){ xv[q]=xr[q];
            xs += xv[q].x*xv[q].x + xv[q].y*xv[q].y + xv[q].z*xv[q].z + xv[q].w*xv[q].w; }
        float dk[KK];
        #pragma unroll
        for (int k=0;k<KK;++k){
            const float4* cr = (const float4*)(&c_s[k][0]);
            float dot=0.f;
            #pragma unroll
            for (int q=0;q<16;++q){ float4 cv=cr[q];
                dot += xv[q].x*cv.x + xv[q].y*cv.y + xv[q].z*cv.z + xv[q].w*cv.w; }
            dk[k] = xs + csq_s[k] - 2.f*dot;
        }
        float dmin = dk[0]; int am=0;
        #pragma unroll
        for (int k=1;k<KK;++k){ if (dk[k] < dmin){ dmin=dk[k]; am=k; } }
        float se=0.f; float ek[KK];
        #pragma unroll
        for (int k=0;k<KK;++k){ ek[k] = ex2((dmin-dk[k])*LOG2E); se+=ek[k]; }
        float inv = 1.f/se;
        #pragma unroll
        for (int k=0;k<KK;++k) atomicAdd(&fpart[k], ek[k]*inv);
        wf[U_XSQ + i] = xs;
        wi[U_PRED + i] = am;
        atomicAdd(&wi[U_CNTX + am], 1);
    }
    __syncthreads();
    if (tid < KK) atomicAdd(&wf[U_FILL + tid], fpart[tid]);
}

// ---------------- kernel 2: per-target: norms + counts ----------------
__global__ __launch_bounds__(256) void k_prep_y(const float* __restrict__ y,
                                                const int* __restrict__ predt,
                                                float* wf, int* wi) {
    int j = blockIdx.x*256 + threadIdx.x;
    if (j < MM) {
        const float4* yr = (const float4*)(y + (size_t)j*DD);
        float s=0.f;
        #pragma unroll
        for (int q=0;q<16;++q){ float4 v=yr[q]; s += v.x*v.x+v.y*v.y+v.z*v.z+v.w*v.w; }
        wf[U_YSQ + j] = s;
        atomicAdd(&wi[U_CNTY + predt[j]], 1);
    }
}

// ---------------- kernel 3: prefix sums, problem tables, loss_fil ----------------
__global__ void k_offsets(const float* __restrict__ ftarg, float* wf, int* wi, float* out) {
    if (threadIdx.x != 0) return;
    int offx=0, offy=0;
    wi[U_OFFX]=0; wi[U_OFFY]=0;
    for (int k=0;k<KK;++k){
        offx += wi[U_CNTX+k]; wi[U_OFFX+k+1]=offx;
        offy += wi[U_CNTY+k]; wi[U_OFFY+k+1]=offy;
    }
    int co=0, to=0;
    for (int k=0;k<KK;++k){
        int cx=wi[U_CNTX+k], cy=wi[U_CNTY+k];
        bool val = (cx>0)&&(cy>0);
        for (int t=0;t<3;++t){
            int p=k*3+t;
            int nx = val ? (t==2?cy:cx) : 0;
            int ny = val ? (t==1?cx:cy) : 0;
            wi[U_PNX+p]=nx; wi[U_PNY+p]=ny;
            wi[U_PRB+p] = (t==2)? wi[U_OFFY+k] : wi[U_OFFX+k];
            wi[U_PCB+p] = (t==1)? wi[U_OFFX+k] : wi[U_OFFY+k];
            wi[U_PRS+p] = (t==2)?1:0;
            wi[U_PCS+p] = (t==1)?0:1;
            wi[U_PCOFF+p]=co; co += nx*ny;
            wi[U_TOFF+p]=to; to += ((nx+31)>>5)*((ny+31)>>5);
        }
    }
    wi[U_PCOFF+NPROB]=co; wi[U_TOFF+NPROB]=to;
    float lf=0.f;
    for (int k=0;k<KK;++k){ float fx = wf[U_FILL+k]/(float)NN; float dd = fx - ftarg[k]; lf += dd*dd; }
    out[0] = lf/(float)KK;
}

// ---------------- kernel 4: scatter compact index lists ----------------
__global__ __launch_bounds__(256) void k_scatter(const int* __restrict__ predt, int* wi) {
    int b = blockIdx.x;
    if (b < 12) {
        int i = b*256 + threadIdx.x;
        if (i < NN){ int k = wi[U_PRED+i]; int p = atomicAdd(&wi[U_POSX+k],1);
                     wi[U_ROWS + wi[U_OFFX+k] + p] = i; }
    } else {
        int j = (b-12)*256 + threadIdx.x;
        if (j < MM){ int k = predt[j]; int p = atomicAdd(&wi[U_POSY+k],1);
                     wi[U_COLS + wi[U_OFFY+k] + p] = j; }
    }
}

// ---------------- kernel 5: exact max over full cost matrices (tiled) ----------------
__global__ __launch_bounds__(256) void k_maxmat(const float* __restrict__ x,
                                                const float* __restrict__ y,
                                                float* wf, int* wi) {
    int z = blockIdx.z;
    const float* A = (z==2)? y : x;
    const float* B = (z==0)? y : ((z==1)? x : y);
    int aqo = (z==2)? U_YSQ : U_XSQ;
    int bqo = (z==1)? U_XSQ : U_YSQ;
    __shared__ float la[64][65];
    __shared__ float lb[64][65];
    __shared__ float laq[64], lbq[64];
    __shared__ float wred[4];
    int tid = threadIdx.x;
    int i0 = blockIdx.y*64, j0 = blockIdx.x*64;
    #pragma unroll
    for (int q=0;q<4;++q){
        int idx4 = tid + q*256;
        int r = idx4>>4; int c = (idx4&15)<<2;
        float4 va = *(const float4*)(A + (size_t)(i0+r)*DD + c);
        la[r][c]=va.x; la[r][c+1]=va.y; la[r][c+2]=va.z; la[r][c+3]=va.w;
        float4 vb = *(const float4*)(B + (size_t)(j0+r)*DD + c);
        lb[r][c]=vb.x; lb[r][c+1]=vb.y; lb[r][c+2]=vb.z; lb[r][c+3]=vb.w;
    }
    if (tid < 64) { laq[tid]=wf[aqo+i0+tid]; lbq[tid]=wf[bqo+j0+tid]; }
    __syncthreads();
    int r0 = (tid>>4)<<2, c0 = (tid&15)<<2;
    float acc[4][4] = {};
    for (int d=0; d<DD; ++d){
        float av[4], bv[4];
        #pragma unroll
        for (int a=0;a<4;++a){ av[a]=la[r0+a][d]; bv[a]=lb[c0+a][d]; }
        #pragma unroll
        for (int a=0;a<4;++a)
            #pragma unroll
            for (int b2=0;b2<4;++b2) acc[a][b2] += av[a]*bv[b2];
    }
    float m = 0.f;
    #pragma unroll
    for (int a=0;a<4;++a)
        #pragma unroll
        for (int b2=0;b2<4;++b2){
            float cst = 0.5f*(laq[r0+a]+lbq[c0+b2]) - acc[a][b2];
            m = fmaxf(m, cst);
        }
    #pragma unroll
    for (int o=32;o;o>>=1) m = fmaxf(m, __shfl_xor(m,o));
    int wid = tid>>6;
    if ((tid&63)==0) wred[wid]=m;
    __syncthreads();
    if (tid==0){
        float mm = fmaxf(fmaxf(wred[0],wred[1]),fmaxf(wred[2],wred[3]));
        atomicMax((unsigned int*)&wi[U_MAXC+z], __float_as_uint(mm));
    }
}

// ---------------- kernel 6: gather compact per-problem cost submatrices ----------------
__global__ __launch_bounds__(256) void k_gather(const float* __restrict__ x,
                                                const float* __restrict__ y,
                                                float* wf, int* wi) {
    __shared__ float xs_[32][65], ys_[32][65];
    __shared__ float rq[32], cq[32];
    __shared__ int toff_s[NPROB+1];
    int tid = threadIdx.x;
    if (tid <= NPROB) toff_s[tid] = wi[U_TOFF+tid];
    __syncthreads();
    int total = toff_s[NPROB];
    for (int tix = blockIdx.x; tix < total; tix += gridDim.x){
        int p = 0;
        while (toff_s[p+1] <= tix) ++p;
        int nx = wi[U_PNX+p], ny = wi[U_PNY+p];
        int tpr = (ny+31)>>5;
        int loc = tix - toff_s[p];
        int i0 = (loc/tpr)<<5, j0 = (loc%tpr)<<5;
        int rbase = wi[U_PRB+p], cbase = wi[U_PCB+p];
        int rs = wi[U_PRS+p], cs = wi[U_PCS+p];
        const float* rsrc = rs? y : x;
        const float* csrc = cs? y : x;
        const int* rlist = wi + (rs? U_COLS : U_ROWS);
        const int* clist = wi + (cs? U_COLS : U_ROWS);
        int rqo = rs? U_YSQ : U_XSQ;
        int cqo = cs? U_YSQ : U_XSQ;
        size_t coff = (size_t)wi[U_PCOFF+p];
        #pragma unroll
        for (int q=0;q<2;++q){
            int idx4 = tid + q*256;      // 0..511
            int r = idx4>>4, c = (idx4&15)<<2;
            if (i0 + r < nx){
                int gi = rlist[rbase + i0 + r];
                float4 v = *(const float4*)(rsrc + (size_t)gi*DD + c);
                xs_[r][c]=v.x; xs_[r][c+1]=v.y; xs_[r][c+2]=v.z; xs_[r][c+3]=v.w;
                if (c==0) rq[r] = wf[rqo + gi];
            }
            if (j0 + r < ny){
                int gj = clist[cbase + j0 + r];
                float4 v = *(const float4*)(csrc + (size_t)gj*DD + c);
                ys_[r][c]=v.x; ys_[r][c+1]=v.y; ys_[r][c+2]=v.z; ys_[r][c+3]=v.w;
                if (c==0) cq[r] = wf[cqo + gj];
            }
        }
        __syncthreads();
        int r = tid>>3, cb = (tid&7)<<2;
        if (i0 + r < nx){
            float acc[4] = {0.f,0.f,0.f,0.f};
            for (int d=0; d<DD; ++d){
                float xv = xs_[r][d];
                #pragma unroll
                for (int q=0;q<4;++q) acc[q] += xv*ys_[cb+q][d];
            }
            float* dst = wf + U_SUBC + coff + (size_t)(i0+r)*ny + j0;
            #pragma unroll
            for (int q=0;q<4;++q){
                int j = cb+q;
                if (j0 + j < ny) dst[j] = 0.5f*(rq[r]+cq[j]) - acc[q];
            }
        }
        __syncthreads();
    }
}

// ---------------- kernel 7: per-problem restricted Sinkhorn (1 block / problem) ----------------
__global__ __launch_bounds__(1024) void k_sinkhorn(float* wf, int* wi, float* out) {
    int p = blockIdx.x;
    int nx = wi[U_PNX+p], ny = wi[U_PNY+p];
    if (nx<=0 || ny<=0) return;
    int t = p % 3;
    float wgt = (t==0)? 1.f : -0.5f;
    const float* C = wf + U_SUBC + (size_t)wi[U_PCOFF+p];
    float maxC = __uint_as_float((unsigned)wi[U_MAXC+t]);
    float eps0 = fmaxf(maxC, C_EPS);
    float ln_nx = lg2((float)nx)*LN2F;     // = ln(nx) = -loga
    float ln_ny = lg2((float)ny)*LN2F;     // = ln(ny) = -logb
    __shared__ float f_s[NN], g_s[MM], sc[NN];
    __shared__ float pm[16*64], ps[16*64];
    __shared__ float acc2[2];
    int tid = threadIdx.x, wid = tid>>6, lane = tid&63;
    for (int j=tid;j<ny;j+=1024) g_s[j]=0.f;
    for (int i=tid;i<nx;i+=1024) f_s[i]=0.f;
    if (tid<2) acc2[tid]=0.f;
    float eps_cur = eps0;
    for (int it=0; it<=C_NITER; ++it){
        bool fin = (it==C_NITER);
        float eps = fin ? C_EPS : fmaxf(eps_cur, C_EPS);
        float ie2 = LOG2E/eps;
        float neL = -eps*LN2F;
        __syncthreads();                       // g_s ready / sc free
        for (int j=tid;j<ny;j+=1024) sc[j]=g_s[j]*ie2;
        __syncthreads();
        // ---- f-phase: wave per row, lanes over columns ----
        for (int i=wid; i<nx; i+=16){
            const float* Cr = C + (size_t)i*ny;
            float m = -FLT_MAX;
            for (int j=lane;j<ny;j+=64) m = fmaxf(m, fmaf(Cr[j], -ie2, sc[j]));
            #pragma unroll
            for (int o=32;o;o>>=1) m = fmaxf(m, __shfl_xor(m,o));
            float S = 0.f;
            for (int j=lane;j<ny;j+=64){ float u = fmaf(Cr[j], -ie2, sc[j]); S += ex2(u-m); }
            #pragma unroll
            for (int o=32;o;o>>=1) S += __shfl_xor(S,o);
            if (lane==0){
                float val = neL*(m + lg2(S)) + eps*ln_ny;
                if (!fin) f_s[i] = val; else atomicAdd(&acc2[0], val);
            }
        }
        __syncthreads();
        for (int i=tid;i<nx;i+=1024) sc[i]=f_s[i]*ie2;
        __syncthreads();
        // ---- g-phase: lanes across columns, serial down rows ----
        int ngr = (ny+63)>>6;
        if (ngr >= 16){
            for (int grp=wid; grp<ngr; grp+=16){
                int j = (grp<<6)+lane;
                bool v = j<ny;
                float val = 0.f;
                if (v){
                    const float* Cc = C + j;
                    float m=-FLT_MAX;
                    for (int i2=0;i2<nx;++i2) m = fmaxf(m, fmaf(Cc[(size_t)i2*ny], -ie2, sc[i2]));
                    float S=0.f;
                    for (int i2=0;i2<nx;++i2){ float u = fmaf(Cc[(size_t)i2*ny], -ie2, sc[i2]); S += ex2(u-m); }
                    val = neL*(m + lg2(S)) + eps*ln_nx;
                    if (!fin) g_s[j]=val;
                }
                if (fin){
                    float sv = v? val : 0.f;
                    #pragma unroll
                    for (int o=32;o;o>>=1) sv += __shfl_xor(sv,o);
                    if (lane==0) atomicAdd(&acc2[1], sv);
                }
            }
        } else {
            int nsl = 16/ngr;
            int grp = wid % ngr, sl = wid / ngr;
            float m=-FLT_MAX, S=0.f;
            int j = (grp<<6)+lane;
            if (sl<nsl && j<ny){
                int ib = (int)(((long long)sl*nx)/nsl), ie_ = (int)(((long long)(sl+1)*nx)/nsl);
                const float* Cc = C + j;
                for (int i2=ib;i2<ie_;++i2) m = fmaxf(m, fmaf(Cc[(size_t)i2*ny], -ie2, sc[i2]));
                for (int i2=ib;i2<ie_;++i2){ float u = fmaf(Cc[(size_t)i2*ny], -ie2, sc[i2]); S += ex2(u-m); }
            }
            if (sl<nsl){ pm[wid*64+lane]=m; ps[wid*64+lane]=S; }
            __syncthreads();
            if (wid < ngr){
                int j2 = (wid<<6)+lane;
                float mm=-FLT_MAX;
                for (int s2=0;s2<nsl;++s2) mm = fmaxf(mm, pm[(s2*ngr+wid)*64+lane]);
                float SS=0.f;
                for (int s2=0;s2<nsl;++s2) SS += ps[(s2*ngr+wid)*64+lane]*ex2(pm[(s2*ngr+wid)*64+lane]-mm);
                bool v = j2<ny;
                float val = 0.f;
                if (v) val = neL*(mm + lg2(SS)) + eps*ln_nx;
                if (!fin){ if (v) g_s[j2]=val; }
                else {
                    float sv = v? val : 0.f;
                    #pragma unroll
                    for (int o=32;o;o>>=1) sv += __shfl_xor(sv,o);
                    if (lane==0) atomicAdd(&acc2[1], sv);
                }
            }
        }
        eps_cur *= C_SCAL2;
    }
    __syncthreads();
    if (tid==0){
        float s = acc2[0]/(float)nx + acc2[1]/(float)ny;
        atomicAdd(out, wgt*s);
    }
}

extern "C" void kernel_launch(void* const* d_in, const int* in_sizes, int n_in,
                              void* d_out, int out_size, void* d_ws, size_t ws_size,
                              hipStream_t stream) {
    const float* x     = (const float*)d_in[0];
    const float* y     = (const float*)d_in[1];
    const float* cc    = (const float*)d_in[2];
    const float* ft    = (const float*)d_in[3];
    const int*   predt = (const int*)d_in[4];
    float* out = (float*)d_out;
    float* wf = (float*)d_ws;
    int*   wi = (int*)d_ws;

    hipMemsetAsync(d_ws, 0, 44*sizeof(int), stream);   // counters / maxes / fillings

    k_prep_x<<<12, 256, 0, stream>>>(x, cc, wf, wi);
    k_prep_y<<<12, 256, 0, stream>>>(y, predt, wf, wi);
    k_offsets<<<1, 64, 0, stream>>>(ft, wf, wi, out);  // also writes out[0] = loss_fil
    k_scatter<<<24, 256, 0, stream>>>(predt, wi);
    k_maxmat<<<dim3(48,48,3), 256, 0, stream>>>(x, y, wf, wi);
    k_gather<<<1024, 256, 0, stream>>>(x, y, wf, wi);
    k_sinkhorn<<<24, 1024, 0, stream>>>(wf, wi, out);
}

// Round 2
// 1061.505 us; speedup vs baseline: 9.4383x; 9.4383x over previous
//
#include <hip/hip_runtime.h>
#include <hip/hip_bf16.h>
#include <float.h>

#define NN 3072
#define MM 3072
#define DD 64
#define KK 8
#define NPROB 24

constexpr float C_EPS   = 0.0025f;   // blur^2
constexpr float C_SCAL2 = 0.64f;     // scaling^2
constexpr int   C_NITER = 30;
constexpr float LOG2E = 1.4426950408889634f;
constexpr float LN2F  = 0.6931471805599453f;
constexpr float L2_SCAL2 = -0.6438561897747247f;   // log2(0.64)

__device__ __forceinline__ float ex2(float x){ return __builtin_amdgcn_exp2f(x); }
__device__ __forceinline__ float lg2(float x){ return __builtin_amdgcn_logf(x); }

// workspace layout in 4-byte units
#define U_FILL 0        // 8 floats  (zeroed by memset)
#define U_MAXC 8        // 4 uints   (zeroed)
#define U_CNTX 12       // 8 int     (zeroed)
#define U_CNTY 20       // 8 int     (zeroed)
#define U_POSX 28       // 8 int     (zeroed)
#define U_POSY 36       // 8 int     (zeroed)  -> memset covers [0,44)
#define U_OFFX 44       // 9 int
#define U_OFFY 53       // 9 int
#define U_PNX  64       // 24 int
#define U_PNY  88
#define U_PRB  112
#define U_PCB  136
#define U_PRS  160
#define U_PCS  184
#define U_PCOFF 208     // 25 int
#define U_TOFF  233     // 25 int
#define U_FTOF  258     // 25 int  (prefix of ceil(nx/8))
#define U_GTOF  283     // 25 int  (prefix of ceil(ny/64))
#define U_ACCF  308     // 24 float (zeroed in k_offsets)
#define U_ACCG  332     // 24 float
#define U_XSQ  384      // 3072 float
#define U_YSQ  3456     // 3072 float
#define U_PRED 6528     // 3072 int
#define U_ROWS 9600     // 3072 int
#define U_COLS 12672    // 3072 int
#define U_FPOT 15744    // 24*3072 float potentials f
#define U_GPOT 89472    // 24*3072 float potentials g
#define U_SUBC 163200   // compact submatrices (floats)

// ---------------- kernel 1: per-x-point: norms, argmin, softmax filling ----------------
__global__ __launch_bounds__(256) void k_prep_x(const float* __restrict__ x,
                                                const float* __restrict__ cc,
                                                float* wf, int* wi) {
    __shared__ __align__(16) float c_s[KK][DD];
    __shared__ float csq_s[KK];
    __shared__ float fpart[KK];
    int tid = threadIdx.x;
    for (int e = tid; e < KK*DD; e += 256) c_s[e>>6][e&63] = cc[e];
    if (tid < KK) fpart[tid] = 0.f;
    __syncthreads();
    if (tid < KK) { float s=0.f; for (int d=0; d<DD; ++d){ float v=c_s[tid][d]; s+=v*v; } csq_s[tid]=s; }
    __syncthreads();
    int i = blockIdx.x*256 + tid;
    if (i < NN) {
        const float4* xr = (const float4*)(x + (size_t)i*DD);
        float4 xv[16];
        float xs = 0.f;
        #pragma unroll
        for (int q=0;q<16;++q){ xv[q]=xr[q];
            xs += xv[q].x*xv[q].x + xv[q].y*xv[q].y + xv[q].z*xv[q].z + xv[q].w*xv[q].w; }
        float dk[KK];
        #pragma unroll
        for (int k=0;k<KK;++k){
            const float4* cr = (const float4*)(&c_s[k][0]);
            float dot=0.f;
            #pragma unroll
            for (int q=0;q<16;++q){ float4 cv=cr[q];
                dot += xv[q].x*cv.x + xv[q].y*cv.y + xv[q].z*cv.z + xv[q].w*cv.w; }
            dk[k] = xs + csq_s[k] - 2.f*dot;
        }
        float dmin = dk[0]; int am=0;
        #pragma unroll
        for (int k=1;k<KK;++k){ if (dk[k] < dmin){ dmin=dk[k]; am=k; } }
        float se=0.f; float ek[KK];
        #pragma unroll
        for (int k=0;k<KK;++k){ ek[k] = ex2((dmin-dk[k])*LOG2E); se+=ek[k]; }
        float inv = 1.f/se;
        #pragma unroll
        for (int k=0;k<KK;++k) atomicAdd(&fpart[k], ek[k]*inv);
        wf[U_XSQ + i] = xs;
        wi[U_PRED + i] = am;
        atomicAdd(&wi[U_CNTX + am], 1);
    }
    __syncthreads();
    if (tid < KK) atomicAdd(&wf[U_FILL + tid], fpart[tid]);
}

// ---------------- kernel 2: per-target: norms + counts ----------------
__global__ __launch_bounds__(256) void k_prep_y(const float* __restrict__ y,
                                                const int* __restrict__ predt,
                                                float* wf, int* wi) {
    int j = blockIdx.x*256 + threadIdx.x;
    if (j < MM) {
        const float4* yr = (const float4*)(y + (size_t)j*DD);
        float s=0.f;
        #pragma unroll
        for (int q=0;q<16;++q){ float4 v=yr[q]; s += v.x*v.x+v.y*v.y+v.z*v.z+v.w*v.w; }
        wf[U_YSQ + j] = s;
        atomicAdd(&wi[U_CNTY + predt[j]], 1);
    }
}

// ---------------- kernel 3: prefix sums, problem tables, loss_fil ----------------
__global__ void k_offsets(const float* __restrict__ ftarg, float* wf, int* wi, float* out) {
    if (threadIdx.x != 0) return;
    int offx=0, offy=0;
    wi[U_OFFX]=0; wi[U_OFFY]=0;
    for (int k=0;k<KK;++k){
        offx += wi[U_CNTX+k]; wi[U_OFFX+k+1]=offx;
        offy += wi[U_CNTY+k]; wi[U_OFFY+k+1]=offy;
    }
    int co=0, to=0, fo=0, go=0;
    for (int k=0;k<KK;++k){
        int cx=wi[U_CNTX+k], cy=wi[U_CNTY+k];
        bool val = (cx>0)&&(cy>0);
        for (int t=0;t<3;++t){
            int p=k*3+t;
            int nx = val ? (t==2?cy:cx) : 0;
            int ny = val ? (t==1?cx:cy) : 0;
            wi[U_PNX+p]=nx; wi[U_PNY+p]=ny;
            wi[U_PRB+p] = (t==2)? wi[U_OFFY+k] : wi[U_OFFX+k];
            wi[U_PCB+p] = (t==1)? wi[U_OFFX+k] : wi[U_OFFY+k];
            wi[U_PRS+p] = (t==2)?1:0;
            wi[U_PCS+p] = (t==1)?0:1;
            wi[U_PCOFF+p]=co; co += nx*ny;
            wi[U_TOFF+p]=to; to += ((nx+31)>>5)*((ny+31)>>5);
            wi[U_FTOF+p]=fo; fo += (nx+7)>>3;
            wi[U_GTOF+p]=go; go += (ny+63)>>6;
            wf[U_ACCF+p]=0.f; wf[U_ACCG+p]=0.f;
        }
    }
    wi[U_PCOFF+NPROB]=co; wi[U_TOFF+NPROB]=to;
    wi[U_FTOF+NPROB]=fo;  wi[U_GTOF+NPROB]=go;
    float lf=0.f;
    for (int k=0;k<KK;++k){ float fx = wf[U_FILL+k]/(float)NN; float dd = fx - ftarg[k]; lf += dd*dd; }
    out[0] = lf/(float)KK;
}

// ---------------- kernel 4: scatter compact index lists ----------------
__global__ __launch_bounds__(256) void k_scatter(const int* __restrict__ predt, int* wi) {
    int b = blockIdx.x;
    if (b < 12) {
        int i = b*256 + threadIdx.x;
        if (i < NN){ int k = wi[U_PRED+i]; int p = atomicAdd(&wi[U_POSX+k],1);
                     wi[U_ROWS + wi[U_OFFX+k] + p] = i; }
    } else {
        int j = (b-12)*256 + threadIdx.x;
        if (j < MM){ int k = predt[j]; int p = atomicAdd(&wi[U_POSY+k],1);
                     wi[U_COLS + wi[U_OFFY+k] + p] = j; }
    }
}

// ---------------- kernel 5: exact max over full cost matrices (tiled) ----------------
__global__ __launch_bounds__(256) void k_maxmat(const float* __restrict__ x,
                                                const float* __restrict__ y,
                                                float* wf, int* wi) {
    int z = blockIdx.z;
    const float* A = (z==2)? y : x;
    const float* B = (z==0)? y : ((z==1)? x : y);
    int aqo = (z==2)? U_YSQ : U_XSQ;
    int bqo = (z==1)? U_XSQ : U_YSQ;
    __shared__ float la[64][65];
    __shared__ float lb[64][65];
    __shared__ float laq[64], lbq[64];
    __shared__ float wred[4];
    int tid = threadIdx.x;
    int i0 = blockIdx.y*64, j0 = blockIdx.x*64;
    #pragma unroll
    for (int q=0;q<4;++q){
        int idx4 = tid + q*256;
        int r = idx4>>4; int c = (idx4&15)<<2;
        float4 va = *(const float4*)(A + (size_t)(i0+r)*DD + c);
        la[r][c]=va.x; la[r][c+1]=va.y; la[r][c+2]=va.z; la[r][c+3]=va.w;
        float4 vb = *(const float4*)(B + (size_t)(j0+r)*DD + c);
        lb[r][c]=vb.x; lb[r][c+1]=vb.y; lb[r][c+2]=vb.z; lb[r][c+3]=vb.w;
    }
    if (tid < 64) { laq[tid]=wf[aqo+i0+tid]; lbq[tid]=wf[bqo+j0+tid]; }
    __syncthreads();
    int r0 = (tid>>4)<<2, c0 = (tid&15)<<2;
    float acc[4][4] = {};
    for (int d=0; d<DD; ++d){
        float av[4], bv[4];
        #pragma unroll
        for (int a=0;a<4;++a){ av[a]=la[r0+a][d]; bv[a]=lb[c0+a][d]; }
        #pragma unroll
        for (int a=0;a<4;++a)
            #pragma unroll
            for (int b2=0;b2<4;++b2) acc[a][b2] += av[a]*bv[b2];
    }
    float m = 0.f;
    #pragma unroll
    for (int a=0;a<4;++a)
        #pragma unroll
        for (int b2=0;b2<4;++b2){
            float cst = 0.5f*(laq[r0+a]+lbq[c0+b2]) - acc[a][b2];
            m = fmaxf(m, cst);
        }
    #pragma unroll
    for (int o=32;o;o>>=1) m = fmaxf(m, __shfl_xor(m,o));
    int wid = tid>>6;
    if ((tid&63)==0) wred[wid]=m;
    __syncthreads();
    if (tid==0){
        float mm = fmaxf(fmaxf(wred[0],wred[1]),fmaxf(wred[2],wred[3]));
        atomicMax((unsigned int*)&wi[U_MAXC+z], __float_as_uint(mm));
    }
}

// ---------------- kernel 6: gather compact per-problem cost submatrices ----------------
__global__ __launch_bounds__(256) void k_gather(const float* __restrict__ x,
                                                const float* __restrict__ y,
                                                float* wf, int* wi) {
    __shared__ float xs_[32][65], ys_[32][65];
    __shared__ float rq[32], cq[32];
    __shared__ int toff_s[NPROB+1];
    int tid = threadIdx.x;
    if (tid <= NPROB) toff_s[tid] = wi[U_TOFF+tid];
    __syncthreads();
    int total = toff_s[NPROB];
    for (int tix = blockIdx.x; tix < total; tix += gridDim.x){
        int p = 0;
        while (toff_s[p+1] <= tix) ++p;
        int nx = wi[U_PNX+p], ny = wi[U_PNY+p];
        int tpr = (ny+31)>>5;
        int loc = tix - toff_s[p];
        int i0 = (loc/tpr)<<5, j0 = (loc%tpr)<<5;
        int rbase = wi[U_PRB+p], cbase = wi[U_PCB+p];
        int rs = wi[U_PRS+p], cs = wi[U_PCS+p];
        const float* rsrc = rs? y : x;
        const float* csrc = cs? y : x;
        const int* rlist = wi + (rs? U_COLS : U_ROWS);
        const int* clist = wi + (cs? U_COLS : U_ROWS);
        int rqo = rs? U_YSQ : U_XSQ;
        int cqo = cs? U_YSQ : U_XSQ;
        size_t coff = (size_t)wi[U_PCOFF+p];
        #pragma unroll
        for (int q=0;q<2;++q){
            int idx4 = tid + q*256;      // 0..511
            int r = idx4>>4, c = (idx4&15)<<2;
            if (i0 + r < nx){
                int gi = rlist[rbase + i0 + r];
                float4 v = *(const float4*)(rsrc + (size_t)gi*DD + c);
                xs_[r][c]=v.x; xs_[r][c+1]=v.y; xs_[r][c+2]=v.z; xs_[r][c+3]=v.w;
                if (c==0) rq[r] = wf[rqo + gi];
            }
            if (j0 + r < ny){
                int gj = clist[cbase + j0 + r];
                float4 v = *(const float4*)(csrc + (size_t)gj*DD + c);
                ys_[r][c]=v.x; ys_[r][c+1]=v.y; ys_[r][c+2]=v.z; ys_[r][c+3]=v.w;
                if (c==0) cq[r] = wf[cqo + gj];
            }
        }
        __syncthreads();
        int r = tid>>3, cb = (tid&7)<<2;
        if (i0 + r < nx){
            float acc[4] = {0.f,0.f,0.f,0.f};
            for (int d=0; d<DD; ++d){
                float xv = xs_[r][d];
                #pragma unroll
                for (int q=0;q<4;++q) acc[q] += xv*ys_[cb+q][d];
            }
            float* dst = wf + U_SUBC + coff + (size_t)(i0+r)*ny + j0;
            #pragma unroll
            for (int q=0;q<4;++q){
                int j = cb+q;
                if (j0 + j < ny) dst[j] = 0.5f*(rq[r]+cq[j]) - acc[q];
            }
        }
        __syncthreads();
    }
}

// ---------------- helper: per-problem eps for iteration it ----------------
__device__ __forceinline__ float eps_of(const int* wi, int p, int it, int fin){
    if (fin) return C_EPS;
    float eps0 = fmaxf(__uint_as_float((unsigned)wi[U_MAXC + (p%3)]), C_EPS);
    return fmaxf(eps0 * ex2((float)it * L2_SCAL2), C_EPS);
}

// ---------------- kernel 7a: f-update (one phase; launch-per-iteration) ----------------
// block = 512 (8 waves), each wave owns one row; 8 rows per tile.
__global__ __launch_bounds__(512) void k_f(float* wf, int* wi, int it, int fin) {
    __shared__ int toff[NPROB+1];
    __shared__ float gsc[3072];
    int tid = threadIdx.x;
    if (tid <= NPROB) toff[tid] = wi[U_FTOF+tid];
    __syncthreads();
    int total = toff[NPROB];
    for (int tix = blockIdx.x; tix < total; tix += gridDim.x){
        int p = 0;
        while (toff[p+1] <= tix) ++p;
        int nx = wi[U_PNX+p], ny = wi[U_PNY+p];
        float eps = eps_of(wi, p, it, fin);
        float ie2 = LOG2E/eps;
        float neL = -eps*LN2F;
        float l2ny = lg2((float)ny);
        const float* C = wf + U_SUBC + (size_t)wi[U_PCOFF+p];
        const float* g = wf + U_GPOT + p*3072;
        __syncthreads();                    // previous tile done with gsc
        for (int j=tid; j<ny; j+=512) gsc[j] = g[j]*ie2;
        __syncthreads();
        int w = tid>>6, lane = tid&63;
        int i = ((tix - toff[p])<<3) + w;
        if (i < nx){
            const float* Cr = C + (size_t)i*ny;
            float m = -FLT_MAX, S = 0.f;
            for (int j=lane; j<ny; j+=64){
                float u = fmaf(Cr[j], -ie2, gsc[j]);
                float mn = fmaxf(m, u);
                S = S*ex2(m-mn) + ex2(u-mn);
                m = mn;
            }
            #pragma unroll
            for (int o=32;o;o>>=1){
                float mo = __shfl_xor(m,o), So = __shfl_xor(S,o);
                float mn = fmaxf(m, mo);
                S = S*ex2(m-mn) + So*ex2(mo-mn);
                m = mn;
            }
            if (lane==0){
                float val = neL*(m + lg2(S) - l2ny);
                if (!fin) wf[U_FPOT + p*3072 + i] = val;
                else      atomicAdd(&wf[U_ACCF+p], val);
            }
        }
    }
}

// ---------------- kernel 7b: g-update ----------------
// block = 512 (8 waves); tile = 64 columns; waves split the rows, LDS-combine.
__global__ __launch_bounds__(512) void k_g(float* wf, int* wi, int it, int fin) {
    __shared__ int toff[NPROB+1];
    __shared__ float fsc[3072];
    __shared__ float pm[8][64], pS[8][64];
    int tid = threadIdx.x;
    if (tid <= NPROB) toff[tid] = wi[U_GTOF+tid];
    __syncthreads();
    int total = toff[NPROB];
    for (int tix = blockIdx.x; tix < total; tix += gridDim.x){
        int p = 0;
        while (toff[p+1] <= tix) ++p;
        int nx = wi[U_PNX+p], ny = wi[U_PNY+p];
        float eps = eps_of(wi, p, it, fin);
        float ie2 = LOG2E/eps;
        float neL = -eps*LN2F;
        float l2nx = lg2((float)nx);
        const float* C = wf + U_SUBC + (size_t)wi[U_PCOFF+p];
        const float* f = wf + U_FPOT + p*3072;
        __syncthreads();                    // previous tile done with fsc/pm/pS
        for (int i2=tid; i2<nx; i2+=512) fsc[i2] = f[i2]*ie2;
        __syncthreads();
        int w = tid>>6, lane = tid&63;
        int j = ((tix - toff[p])<<6) + lane;
        int i0 = (w*nx)>>3, i1 = ((w+1)*nx)>>3;
        float m = -FLT_MAX, S = 0.f;
        if (j < ny){
            const float* Cc = C + j;
            int i2 = i0;
            for (; i2+4 <= i1; i2 += 4){
                float c0 = Cc[(size_t)(i2+0)*ny];
                float c1 = Cc[(size_t)(i2+1)*ny];
                float c2 = Cc[(size_t)(i2+2)*ny];
                float c3 = Cc[(size_t)(i2+3)*ny];
                float u0 = fmaf(c0, -ie2, fsc[i2+0]);
                float u1 = fmaf(c1, -ie2, fsc[i2+1]);
                float u2 = fmaf(c2, -ie2, fsc[i2+2]);
                float u3 = fmaf(c3, -ie2, fsc[i2+3]);
                float ma = fmaxf(fmaxf(u0,u1), fmaxf(u2,u3));
                float mn = fmaxf(m, ma);
                S = S*ex2(m-mn) + ex2(u0-mn) + ex2(u1-mn) + ex2(u2-mn) + ex2(u3-mn);
                m = mn;
            }
            for (; i2 < i1; ++i2){
                float u = fmaf(Cc[(size_t)i2*ny], -ie2, fsc[i2]);
                float mn = fmaxf(m, u);
                S = S*ex2(m-mn) + ex2(u-mn);
                m = mn;
            }
        }
        pm[w][lane] = m; pS[w][lane] = S;
        __syncthreads();
        if (w == 0){
            float mm = pm[0][lane], SS = pS[0][lane];
            #pragma unroll
            for (int q=1;q<8;++q){
                float mo = pm[q][lane], So = pS[q][lane];
                float mn = fmaxf(mm, mo);
                SS = SS*ex2(mm-mn) + So*ex2(mo-mn);
                mm = mn;
            }
            bool vv = (j < ny);
            float val = 0.f;
            if (vv){
                val = neL*(mm + lg2(SS) - l2nx);
                if (!fin) wf[U_GPOT + p*3072 + j] = val;
            }
            if (fin){
                float sv = vv ? val : 0.f;
                #pragma unroll
                for (int o=32;o;o>>=1) sv += __shfl_xor(sv,o);
                if (lane==0) atomicAdd(&wf[U_ACCG+p], sv);
            }
        }
    }
}

// ---------------- kernel 8: finalize ----------------
__global__ void k_final(float* wf, int* wi, float* out) {
    if (threadIdx.x != 0 || blockIdx.x != 0) return;
    float s = 0.f;
    for (int p=0; p<NPROB; ++p){
        int nx = wi[U_PNX+p], ny = wi[U_PNY+p];
        if (nx<=0 || ny<=0) continue;
        float wgt = (p%3==0) ? 1.f : -0.5f;
        s += wgt * (wf[U_ACCF+p]/(float)nx + wf[U_ACCG+p]/(float)ny);
    }
    out[0] += s;
}

extern "C" void kernel_launch(void* const* d_in, const int* in_sizes, int n_in,
                              void* d_out, int out_size, void* d_ws, size_t ws_size,
                              hipStream_t stream) {
    const float* x     = (const float*)d_in[0];
    const float* y     = (const float*)d_in[1];
    const float* cc    = (const float*)d_in[2];
    const float* ft    = (const float*)d_in[3];
    const int*   predt = (const int*)d_in[4];
    float* out = (float*)d_out;
    float* wf = (float*)d_ws;
    int*   wi = (int*)d_ws;

    hipMemsetAsync(d_ws, 0, 44*sizeof(int), stream);                      // counters/maxes/fillings
    hipMemsetAsync(wf + U_GPOT, 0, NPROB*3072*sizeof(float), stream);     // g potentials start at 0

    k_prep_x<<<12, 256, 0, stream>>>(x, cc, wf, wi);
    k_prep_y<<<12, 256, 0, stream>>>(y, predt, wf, wi);
    k_offsets<<<1, 64, 0, stream>>>(ft, wf, wi, out);   // writes out[0] = loss_fil, tables, zero accs
    k_scatter<<<24, 256, 0, stream>>>(predt, wi);
    k_maxmat<<<dim3(48,48,3), 256, 0, stream>>>(x, y, wf, wi);
    k_gather<<<1024, 256, 0, stream>>>(x, y, wf, wi);

    for (int it = 0; it < C_NITER; ++it){
        k_f<<<1024, 512, 0, stream>>>(wf, wi, it, 0);
        k_g<<<256, 512, 0, stream>>>(wf, wi, it, 0);
    }
    k_f<<<1024, 512, 0, stream>>>(wf, wi, C_NITER, 1);  // f2: accumulate, do not overwrite f
    k_g<<<256, 512, 0, stream>>>(wf, wi, C_NITER, 1);   // g2: uses converged f
    k_final<<<1, 64, 0, stream>>>(wf, wi, out);
}